// Round 4
// baseline (164.394 us; speedup 1.0000x reference)
//
#include <hip/hip_runtime.h>

#define N_DIM 4096

typedef float f4  __attribute__((ext_vector_type(4)));
typedef short s8v __attribute__((ext_vector_type(8)));

#if defined(__has_builtin)
#if __has_builtin(__builtin_amdgcn_cvt_pk_bf16_f32)
#define HAVE_CVT_PK 1
#endif
#endif

static __device__ __forceinline__ unsigned int f2bf_pair(float lo, float hi) {
#ifdef HAVE_CVT_PK
    typedef __bf16 bf2 __attribute__((ext_vector_type(2)));
    bf2 p = __builtin_amdgcn_cvt_pk_bf16_f32(lo, hi);
    return __builtin_bit_cast(unsigned int, p);
#else
    unsigned int ul = __builtin_bit_cast(unsigned int, lo);
    unsigned int uh = __builtin_bit_cast(unsigned int, hi);
    ul = ul + 0x7fffu + ((ul >> 16) & 1u);
    uh = uh + 0x7fffu + ((uh >> 16) & 1u);
    return (uh & 0xffff0000u) | (ul >> 16);
#endif
}

static __device__ __forceinline__ s8v cvt8(f4 a, f4 b) {
    unsigned int u4[4] = { f2bf_pair(a[0], a[1]), f2bf_pair(a[2], a[3]),
                           f2bf_pair(b[0], b[1]), f2bf_pair(b[2], b[3]) };
    return __builtin_bit_cast(s8v, u4);
}

__global__ void zero_out_kernel(float* __restrict__ out) {
    if (threadIdx.x == 0 && blockIdx.x == 0) out[0] = 0.f;
}

// One block per 16-row i-tile; 1024 threads = 16 waves = 4 k-slices x 4
// n-quarters. K-loop is LDS-free (fragments are 8 consecutive row elements,
// verified R2/R3 absmax 0.0) and barrier-free; 4 waves/SIMD provide the TLP
// that R3 (1 wave/SIMD) lacked. One LDS pass at the end reduces n-quarters.
__global__ __launch_bounds__(1024) void fused_kernel(
    const float* __restrict__ zs, const float* __restrict__ X,
    const float* __restrict__ varp, float* __restrict__ out) {
    const int tid  = threadIdx.x;
    const int lane = tid & 63;
    const int w    = tid >> 6;
    const int kw   = w & 3;          // k-slice  [16*kw, 16*kw+16)
    const int nw   = w >> 2;         // n-range  [1024*nw, 1024*nw+1024)
    const int i0   = blockIdx.x * 16;
    const int coff = (lane >> 4) * 8;

    const float* pz = zs + (size_t)(16 * kw + (lane & 15)) * N_DIM + nw * 1024 + coff;
    const float* px = X  + (size_t)(i0   + (lane & 15)) * N_DIM + nw * 1024 + coff;

    f4 acc = {0.f, 0.f, 0.f, 0.f};
    f4 za[8], xb[8];

    #pragma unroll
    for (int s = 0; s < 4; ++s) {
        za[2 * s]     = *(const f4*)(pz + s * 32);
        za[2 * s + 1] = *(const f4*)(pz + s * 32 + 4);
        xb[2 * s]     = *(const f4*)(px + s * 32);
        xb[2 * s + 1] = *(const f4*)(px + s * 32 + 4);
    }

    for (int c = 0; c < 8; ++c) {
        s8v af[4], bf[4];
        #pragma unroll
        for (int s = 0; s < 4; ++s) {
            af[s] = cvt8(za[2 * s], za[2 * s + 1]);
            bf[s] = cvt8(xb[2 * s], xb[2 * s + 1]);
        }
        if (c < 7) {
            const float* qz = pz + (c + 1) * 128;
            const float* qx = px + (c + 1) * 128;
            #pragma unroll
            for (int s = 0; s < 4; ++s) {
                za[2 * s]     = *(const f4*)(qz + s * 32);
                za[2 * s + 1] = *(const f4*)(qz + s * 32 + 4);
                xb[2 * s]     = *(const f4*)(qx + s * 32);
                xb[2 * s + 1] = *(const f4*)(qx + s * 32 + 4);
            }
        }
        #pragma unroll
        for (int s = 0; s < 4; ++s)
            acc = __builtin_amdgcn_mfma_f32_16x16x32_bf16(af[s], bf[s], acc, 0, 0, 0);
    }

    // cross-wave reduction over n-quarters, then epilogue on waves 0..3
    __shared__ f4 accs[16][64];
    __shared__ float wsum[4];
    accs[w][lane] = acc;
    __syncthreads();

    if (w < 4) {
        f4 t = accs[w][lane];
        #pragma unroll
        for (int j = 1; j < 4; ++j) {
            f4 u = accs[w + 4 * j][lane];
            t[0] += u[0]; t[1] += u[1]; t[2] += u[2]; t[3] += u[3];
        }
        // C/D layout: col = lane&15 (i), row = (lane>>4)*4 + r (k), k-slice w
        const int   i_g  = i0 + (lane & 15);
        const float diag = X[(size_t)i_g * N_DIM + i_g];
        const float var  = varp[0];
        float lsum = 0.f;
        #pragma unroll
        for (int r = 0; r < 4; ++r) {
            int   k   = 16 * w + ((lane >> 4) << 2) + r;
            float num = zs[(size_t)k * N_DIM + i_g] * diag;   // exact fp32
            float den = t[r] - num;
            lsum += num / (var + den);
        }
        #pragma unroll
        for (int off = 32; off >= 1; off >>= 1) lsum += __shfl_down(lsum, off);
        if (lane == 0) wsum[w] = lsum;
    }
    __syncthreads();
    if (tid == 0)
        atomicAdd(out, -(wsum[0] + wsum[1] + wsum[2] + wsum[3]) * (1.0f / 64.0f));
}

extern "C" void kernel_launch(void* const* d_in, const int* in_sizes, int n_in,
                              void* d_out, int out_size, void* d_ws, size_t ws_size,
                              hipStream_t stream) {
    const float* zs   = (const float*)d_in[0];
    const float* X    = (const float*)d_in[1];
    const float* varp = (const float*)d_in[2];
    float* out = (float*)d_out;

    hipLaunchKernelGGL(zero_out_kernel, dim3(1), dim3(64), 0, stream, out);
    hipLaunchKernelGGL(fused_kernel, dim3(256), dim3(1024), 0, stream, zs, X, varp, out);
}

// Round 5
// 160.351 us; speedup vs baseline: 1.0252x; 1.0252x over previous
//
#include <hip/hip_runtime.h>

#define N_DIM 4096

typedef float f4  __attribute__((ext_vector_type(4)));
typedef short s8v __attribute__((ext_vector_type(8)));

#if defined(__has_builtin)
#if __has_builtin(__builtin_amdgcn_cvt_pk_bf16_f32)
#define HAVE_CVT_PK 1
#endif
#endif

static __device__ __forceinline__ unsigned int f2bf_pair(float lo, float hi) {
#ifdef HAVE_CVT_PK
    typedef __bf16 bf2 __attribute__((ext_vector_type(2)));
    bf2 p = __builtin_amdgcn_cvt_pk_bf16_f32(lo, hi);
    return __builtin_bit_cast(unsigned int, p);
#else
    unsigned int ul = __builtin_bit_cast(unsigned int, lo);
    unsigned int uh = __builtin_bit_cast(unsigned int, hi);
    ul = ul + 0x7fffu + ((ul >> 16) & 1u);
    uh = uh + 0x7fffu + ((uh >> 16) & 1u);
    return (uh & 0xffff0000u) | (ul >> 16);
#endif
}

static __device__ __forceinline__ s8v cvt8(f4 a, f4 b) {
    unsigned int u4[4] = { f2bf_pair(a[0], a[1]), f2bf_pair(a[2], a[3]),
                           f2bf_pair(b[0], b[1]), f2bf_pair(b[2], b[3]) };
    return __builtin_bit_cast(s8v, u4);
}

__global__ void zero_out_kernel(float* __restrict__ out) {
    if (threadIdx.x == 0 && blockIdx.x == 0) out[0] = 0.f;
}

// Partial GEMM: grid (4 n-quarters, 256 i-tiles), 256 threads/block.
// EXACT R3 inner loop (76 VGPR, no spill) over 8 chunks; TLP comes from
// ~4 blocks/CU instead of fat blocks (R4's launch_bounds(1024) capped
// VGPRs at 64 -> 42 MB scratch spill; this keeps the register budget).
// Block stores its 16k x 16i partial tile per wave, disjoint + coalesced.
__global__ __launch_bounds__(256) void gemm_part_kernel(
    const float* __restrict__ zs, const float* __restrict__ X,
    float* __restrict__ part) {
    const int tid  = threadIdx.x;
    const int lane = tid & 63;
    const int w    = tid >> 6;             // k-slice [16w, 16w+16)
    const int i0   = blockIdx.y * 16;
    const int n0   = blockIdx.x * 1024;    // n-quarter
    const int coff = (lane >> 4) * 8;

    const float* pz = zs + (size_t)(16 * w + (lane & 15)) * N_DIM + n0 + coff;
    const float* px = X  + (size_t)(i0   + (lane & 15)) * N_DIM + n0 + coff;

    f4 acc = {0.f, 0.f, 0.f, 0.f};
    f4 za[8], xb[8];

    #pragma unroll
    for (int s = 0; s < 4; ++s) {
        za[2 * s]     = *(const f4*)(pz + s * 32);
        za[2 * s + 1] = *(const f4*)(pz + s * 32 + 4);
        xb[2 * s]     = *(const f4*)(px + s * 32);
        xb[2 * s + 1] = *(const f4*)(px + s * 32 + 4);
    }

    for (int c = 0; c < 8; ++c) {
        s8v af[4], bf[4];
        #pragma unroll
        for (int s = 0; s < 4; ++s) {
            af[s] = cvt8(za[2 * s], za[2 * s + 1]);
            bf[s] = cvt8(xb[2 * s], xb[2 * s + 1]);
        }
        if (c < 7) {
            const float* qz = pz + (c + 1) * 128;
            const float* qx = px + (c + 1) * 128;
            #pragma unroll
            for (int s = 0; s < 4; ++s) {
                za[2 * s]     = *(const f4*)(qz + s * 32);
                za[2 * s + 1] = *(const f4*)(qz + s * 32 + 4);
                xb[2 * s]     = *(const f4*)(qx + s * 32);
                xb[2 * s + 1] = *(const f4*)(qx + s * 32 + 4);
            }
        }
        #pragma unroll
        for (int s = 0; s < 4; ++s)
            acc = __builtin_amdgcn_mfma_f32_16x16x32_bf16(af[s], bf[s], acc, 0, 0, 0);
    }

    // part layout: [nq][i_tile][w][lane] as f4 — disjoint, 16 B/lane coalesced
    ((f4*)part)[((blockIdx.x * 256 + blockIdx.y) * 4 + w) * 64 + lane] = acc;
}

// Epilogue: one thread per (k,i). Sum 4 quarter-partials, exact-fp32 num/den,
// block-reduce, one atomic per block.
__global__ __launch_bounds__(256) void epilogue_kernel(
    const float* __restrict__ part, const float* __restrict__ zs,
    const float* __restrict__ X, const float* __restrict__ varp,
    float* __restrict__ out) {
    const int tid = threadIdx.x;
    const int idx = blockIdx.x * 256 + tid;          // k = idx>>12, i = idx&4095
    const int k = idx >> 12, i = idx & (N_DIM - 1);
    const int it = i >> 4, il = i & 15;
    const int kw = k >> 4, kl = k & 15;
    // acc layout: col = lane&15 (i), row = (lane>>4)*4 + r (k)
    const int lane = ((kl >> 2) << 4) | il;
    const int r    = kl & 3;

    float s = 0.f;
    #pragma unroll
    for (int nq = 0; nq < 4; ++nq)
        s += part[(((nq * 256 + it) * 4 + kw) * 64 + lane) * 4 + r];

    const float num = zs[(size_t)k * N_DIM + i] * X[(size_t)i * (N_DIM + 1)];
    const float den = s - num;
    float v = num / (varp[0] + den);

    #pragma unroll
    for (int off = 32; off >= 1; off >>= 1) v += __shfl_down(v, off);
    __shared__ float wsum[4];
    if ((tid & 63) == 0) wsum[tid >> 6] = v;
    __syncthreads();
    if (tid == 0)
        atomicAdd(out, -(wsum[0] + wsum[1] + wsum[2] + wsum[3]) * (1.0f / 64.0f));
}

extern "C" void kernel_launch(void* const* d_in, const int* in_sizes, int n_in,
                              void* d_out, int out_size, void* d_ws, size_t ws_size,
                              hipStream_t stream) {
    const float* zs   = (const float*)d_in[0];
    const float* X    = (const float*)d_in[1];
    const float* varp = (const float*)d_in[2];
    float* out  = (float*)d_out;
    float* part = (float*)d_ws;   // 4 quarters x 256 tiles x 4 waves x 64 lanes x f4 = 16 MB

    hipLaunchKernelGGL(zero_out_kernel, dim3(1), dim3(64), 0, stream, out);
    hipLaunchKernelGGL(gemm_part_kernel, dim3(4, 256), dim3(256), 0, stream, zs, X, part);
    hipLaunchKernelGGL(epilogue_kernel, dim3((64 * N_DIM) / 256), dim3(256), 0, stream,
                       part, zs, X, varp, out);
}

// Round 6
// 117.239 us; speedup vs baseline: 1.4022x; 1.3677x over previous
//
#include <hip/hip_runtime.h>

#define N_DIM 4096

typedef float f4  __attribute__((ext_vector_type(4)));
typedef short s8v __attribute__((ext_vector_type(8)));

#if defined(__has_builtin)
#if __has_builtin(__builtin_amdgcn_cvt_pk_bf16_f32)
#define HAVE_CVT_PK 1
#endif
#endif

static __device__ __forceinline__ unsigned int f2bf_pair(float lo, float hi) {
#ifdef HAVE_CVT_PK
    typedef __bf16 bf2 __attribute__((ext_vector_type(2)));
    bf2 p = __builtin_amdgcn_cvt_pk_bf16_f32(lo, hi);
    return __builtin_bit_cast(unsigned int, p);
#else
    unsigned int ul = __builtin_bit_cast(unsigned int, lo);
    unsigned int uh = __builtin_bit_cast(unsigned int, hi);
    ul = ul + 0x7fffu + ((ul >> 16) & 1u);
    uh = uh + 0x7fffu + ((uh >> 16) & 1u);
    return (uh & 0xffff0000u) | (ul >> 16);
#endif
}

static __device__ __forceinline__ s8v cvt8(f4 a, f4 b) {
    unsigned int u4[4] = { f2bf_pair(a[0], a[1]), f2bf_pair(a[2], a[3]),
                           f2bf_pair(b[0], b[1]), f2bf_pair(b[2], b[3]) };
    return __builtin_bit_cast(s8v, u4);
}

#define MFMA(a, b, c) __builtin_amdgcn_mfma_f32_16x16x32_bf16((a), (b), (c), 0, 0, 0)

__global__ void zero_out_kernel(float* __restrict__ out) {
    if (threadIdx.x == 0 && blockIdx.x == 0) out[0] = 0.f;
}

// Grid (8 n-eighths, 64 i-tiles), 256 thr. Per 64-col chunk: contiguous 32 B
// per-thread global loads (8 full cache lines per wave-instr — fixes R3/R5's
// 16-way scattered fragment loads), in-reg fp32->bf16, ds_write_b128 into a
// bijective packet layout with full 8-slot bank spread (R1's layout hit only
// 4 slots -> 2.75M conflict cycles). Double-buffered; ONE raw
// s_waitcnt(lgkm)+s_barrier per chunk so next chunk's global loads stay in
// flight across the barrier (no vmcnt(0) drain; parity makes 1 barrier safe).
__global__ __launch_bounds__(256) void gemm_part_kernel(
    const float* __restrict__ zs, const float* __restrict__ X,
    float* __restrict__ part) {
    // packet granule g = (ktile*2 + step)*64 + (row&15 | colsub<<4);
    // fragment read for lane l is granule (kt*2+s)*64 + l  -> lane-linear, dense.
    __shared__ s8v zsP[2][512];   // 64 k  x 64 n bf16, dbuf (16 KB)
    __shared__ s8v xP [2][512];   // 64 i  x 64 n bf16, dbuf (16 KB)

    const int tid  = threadIdx.x;
    const int lane = tid & 63;
    const int w    = tid >> 6;
    const int n0   = blockIdx.x * 512;   // n-eighth
    const int i0   = blockIdx.y * 64;    // i-tile

    // staging decode: thread stages rows r0 and r0+32, cols cid..cid+8 of each chunk
    const int r0  = tid >> 3;            // 0..31
    const int cid = (tid & 7) * 8;
    const int stp = (tid >> 2) & 1;      // cid>>5
    const int csb = tid & 3;             // (cid>>3)&3
    const int g0  = (((r0 >> 4) * 2 + stp) << 6) | (r0 & 15) | (csb << 4);
    const int g1  = ((((r0 + 32) >> 4) * 2 + stp) << 6) | (r0 & 15) | (csb << 4);

    const float* gz0 = zs + (size_t)r0 * N_DIM + n0 + cid;
    const float* gz1 = zs + (size_t)(r0 + 32) * N_DIM + n0 + cid;
    const float* gx0 = X  + (size_t)(i0 + r0) * N_DIM + n0 + cid;
    const float* gx1 = X  + (size_t)(i0 + r0 + 32) * N_DIM + n0 + cid;

    f4 rz[4], rx[4];
    rz[0] = *(const f4*)(gz0);     rz[1] = *(const f4*)(gz0 + 4);
    rz[2] = *(const f4*)(gz1);     rz[3] = *(const f4*)(gz1 + 4);
    rx[0] = *(const f4*)(gx0);     rx[1] = *(const f4*)(gx0 + 4);
    rx[2] = *(const f4*)(gx1);     rx[3] = *(const f4*)(gx1 + 4);

    f4 acc[2][2] = {};
    const int kh = (w & 1) * 2;          // wave's ktiles {kh, kh+1}
    const int ih = (w >> 1) * 2;         // wave's itiles {ih, ih+1}

    for (int c = 0; c < 8; ++c) {
        const int buf = c & 1;
        // convert current chunk (compiler inserts the vmcnt wait here — one
        // chunk of MFMA/LDS work of slack behind it)
        s8v pz0 = cvt8(rz[0], rz[1]);
        s8v pz1 = cvt8(rz[2], rz[3]);
        s8v px0 = cvt8(rx[0], rx[1]);
        s8v px1 = cvt8(rx[2], rx[3]);
        if (c < 7) {  // issue next chunk's loads; they stay in flight across s_barrier
            const int off = (c + 1) * 64;
            rz[0] = *(const f4*)(gz0 + off); rz[1] = *(const f4*)(gz0 + off + 4);
            rz[2] = *(const f4*)(gz1 + off); rz[3] = *(const f4*)(gz1 + off + 4);
            rx[0] = *(const f4*)(gx0 + off); rx[1] = *(const f4*)(gx0 + off + 4);
            rx[2] = *(const f4*)(gx1 + off); rx[3] = *(const f4*)(gx1 + off + 4);
        }
        zsP[buf][g0] = pz0;  zsP[buf][g1] = pz1;
        xP[buf][g0]  = px0;  xP[buf][g1]  = px1;
        // LDS-only drain + raw barrier: does NOT drain vmcnt (unlike __syncthreads)
        asm volatile("s_waitcnt lgkmcnt(0)\n\ts_barrier" ::: "memory");

        s8v a0s0 = zsP[buf][((kh    ) * 2 + 0) * 64 + lane];
        s8v a0s1 = zsP[buf][((kh    ) * 2 + 1) * 64 + lane];
        s8v a1s0 = zsP[buf][((kh + 1) * 2 + 0) * 64 + lane];
        s8v a1s1 = zsP[buf][((kh + 1) * 2 + 1) * 64 + lane];
        s8v b0s0 = xP [buf][((ih    ) * 2 + 0) * 64 + lane];
        s8v b0s1 = xP [buf][((ih    ) * 2 + 1) * 64 + lane];
        s8v b1s0 = xP [buf][((ih + 1) * 2 + 0) * 64 + lane];
        s8v b1s1 = xP [buf][((ih + 1) * 2 + 1) * 64 + lane];

        acc[0][0] = MFMA(a0s0, b0s0, acc[0][0]);
        acc[0][1] = MFMA(a0s0, b1s0, acc[0][1]);
        acc[1][0] = MFMA(a1s0, b0s0, acc[1][0]);
        acc[1][1] = MFMA(a1s0, b1s0, acc[1][1]);
        acc[0][0] = MFMA(a0s1, b0s1, acc[0][0]);
        acc[0][1] = MFMA(a0s1, b1s1, acc[0][1]);
        acc[1][0] = MFMA(a1s1, b0s1, acc[1][0]);
        acc[1][1] = MFMA(a1s1, b1s1, acc[1][1]);
    }

    // partial store: [ne][it][ktile][itile][lane] as f4, disjoint + coalesced
    f4* pp = (f4*)part;
    const int base = (blockIdx.x * 64 + blockIdx.y) * 4;
    #pragma unroll
    for (int a = 0; a < 2; ++a)
        #pragma unroll
        for (int b = 0; b < 2; ++b)
            pp[((base + kh + a) * 4 + ih + b) * 64 + lane] = acc[a][b];
}

// One thread per (k,i): sum 8 n-eighth partials, exact-fp32 num/den, reduce.
__global__ __launch_bounds__(256) void epilogue_kernel(
    const float* __restrict__ part, const float* __restrict__ zs,
    const float* __restrict__ X, const float* __restrict__ varp,
    float* __restrict__ out) {
    const int tid = threadIdx.x;
    const int idx = blockIdx.x * 256 + tid;
    const int k = idx >> 12, i = idx & (N_DIM - 1);
    const int it = i >> 6, itl = (i >> 4) & 3, kt = k >> 4;
    // C/D layout: col = lane&15 (i), row = (lane>>4)*4 + r (k)
    const int lane = ((k & 12) << 2) | (i & 15);
    const int r    = k & 3;

    float s = 0.f;
    #pragma unroll
    for (int ne = 0; ne < 8; ++ne)
        s += part[((((ne * 64 + it) * 4 + kt) * 4 + itl) * 64 + lane) * 4 + r];

    const float num = zs[(size_t)k * N_DIM + i] * X[(size_t)i * (N_DIM + 1)];
    const float den = s - num;
    float v = num / (varp[0] + den);

    #pragma unroll
    for (int off = 32; off >= 1; off >>= 1) v += __shfl_down(v, off);
    __shared__ float wsum[4];
    if ((tid & 63) == 0) wsum[tid >> 6] = v;
    __syncthreads();
    if (tid == 0)
        atomicAdd(out, -(wsum[0] + wsum[1] + wsum[2] + wsum[3]) * (1.0f / 64.0f));
}

extern "C" void kernel_launch(void* const* d_in, const int* in_sizes, int n_in,
                              void* d_out, int out_size, void* d_ws, size_t ws_size,
                              hipStream_t stream) {
    const float* zs   = (const float*)d_in[0];
    const float* X    = (const float*)d_in[1];
    const float* varp = (const float*)d_in[2];
    float* out  = (float*)d_out;
    float* part = (float*)d_ws;   // 8 ne x 64 it x 16 tiles x 64 lanes x 16 B = 8 MB

    hipLaunchKernelGGL(zero_out_kernel, dim3(1), dim3(64), 0, stream, out);
    hipLaunchKernelGGL(gemm_part_kernel, dim3(8, 64), dim3(256), 0, stream, zs, X, part);
    hipLaunchKernelGGL(epilogue_kernel, dim3((64 * N_DIM) / 256), dim3(256), 0, stream,
                       part, zs, X, varp, out);
}